// Round 11
// baseline (285.857 us; speedup 1.0000x reference)
//
#include <hip/hip_runtime.h>
#include <stdint.h>

// ---------- problem constants ----------
#define S_LEN   2048
#define D_MODEL 2048
#define NH      32
#define NKV     8
#define HDIM    64
#define WIN     1024
#define QKV_N   3072
#define MTOT    4096          // B*S
#define QSCALE  0.18033688011112042f   // 0.125 * log2(e)

typedef __bf16 bf16x8 __attribute__((ext_vector_type(8)));
typedef float  f32x4  __attribute__((ext_vector_type(4)));
typedef unsigned short u16x8 __attribute__((ext_vector_type(8)));
typedef unsigned short u16x4 __attribute__((ext_vector_type(4)));

#define GLDS16(g, l) __builtin_amdgcn_global_load_lds( \
    (__attribute__((address_space(1))) void*)(g),      \
    (__attribute__((address_space(3))) void*)(l), 16, 0, 0)

// RNE f32->bf16 via the compiler cast (v_cvt_pk fusion).
__device__ __forceinline__ unsigned short f2bf(float f) {
  __bf16 b = (__bf16)f;
  return __builtin_bit_cast(unsigned short, b);
}

// ---------- fp32 -> bf16 conversion (3 segments, vectorized) ----------
__global__ void cvt3(const float* __restrict__ s0, unsigned short* __restrict__ d0, int n0,
                     const float* __restrict__ s1, unsigned short* __restrict__ d1, int n1,
                     const float* __restrict__ s2, unsigned short* __restrict__ d2, int n2)
{
  int total4 = (n0 + n1 + n2) >> 2;
  for (int idx = blockIdx.x * blockDim.x + threadIdx.x; idx < total4;
       idx += gridDim.x * blockDim.x) {
    int i = idx << 2;
    const float* s; unsigned short* d;
    if (i < n0)            { s = s0 + i;            d = d0 + i; }
    else if (i < n0 + n1)  { s = s1 + (i - n0);     d = d1 + (i - n0); }
    else                   { s = s2 + (i - n0 - n1); d = d2 + (i - n0 - n1); }
    float4 v = *(const float4*)s;
    u16x4 o;
    o[0] = f2bf(v.x); o[1] = f2bf(v.y); o[2] = f2bf(v.z); o[3] = f2bf(v.w);
    *(u16x4*)d = o;
  }
}

// ---------- NT GEMM: C[m,n] = sum_k A[m,k]*B[n,k] (+bias) ----------
// EP==0: QKV epilogue (scatter Q scaled / K row-major / V TRANSPOSED [d][s]).
// EP==1: fp32 out.
template<int EP>
__global__ __launch_bounds__(256)
void gemm_nt(const unsigned short* __restrict__ A, const unsigned short* __restrict__ Bm,
             const float* __restrict__ bias, int K, int N,
             unsigned short* __restrict__ qo, unsigned short* __restrict__ ko,
             unsigned short* __restrict__ vo, float* __restrict__ co)
{
  __shared__ unsigned short sA[128 * 32];
  __shared__ unsigned short sB[128 * 32];
  const int t = threadIdx.x;
  const int l = t & 63;
  const int brow = blockIdx.y << 7;
  const int bcol = blockIdx.x << 7;
  const int wr = ((t >> 7) & 1) << 6;
  const int wc = ((t >> 6) & 1) << 6;

  const int srow  = t >> 2;
  const int skoff = (t & 3) << 3;
  const unsigned short* aP = A + (size_t)(brow + srow) * K + skoff;
  const unsigned short* bP = Bm + (size_t)(bcol + srow) * K + skoff;
  unsigned short* ldsA0 = &sA[(t & 192) << 3];
  unsigned short* ldsA1 = &sA[(256 + (t & 192)) << 3];
  unsigned short* ldsB0 = &sB[(t & 192) << 3];
  unsigned short* ldsB1 = &sB[(256 + (t & 192)) << 3];

  f32x4 acc[4][4] = {};
  const int fr = l & 15;
  const int fk = (l >> 4) << 3;

  for (int kt = 0; kt < K; kt += 32) {
    GLDS16(aP, ldsA0);
    GLDS16(aP + (size_t)64 * K, ldsA1);
    GLDS16(bP, ldsB0);
    GLDS16(bP + (size_t)64 * K, ldsB1);
    aP += 32; bP += 32;
    __syncthreads();

    bf16x8 af[4], bf[4];
#pragma unroll
    for (int mi = 0; mi < 4; ++mi)
      af[mi] = *(const bf16x8*)&sA[(wr + mi * 16 + fr) * 32 + fk];
#pragma unroll
    for (int ni = 0; ni < 4; ++ni)
      bf[ni] = *(const bf16x8*)&sB[(wc + ni * 16 + fr) * 32 + fk];
#pragma unroll
    for (int mi = 0; mi < 4; ++mi)
#pragma unroll
      for (int ni = 0; ni < 4; ++ni)
        acc[mi][ni] = __builtin_amdgcn_mfma_f32_16x16x32_bf16(af[mi], bf[ni], acc[mi][ni], 0, 0, 0);
    __syncthreads();
  }

  const int fq4 = (l >> 4) << 2;
  if (EP == 0) {
#pragma unroll
    for (int ni = 0; ni < 4; ++ni) {
      const int e = bcol + wc + ni * 16 + fr;
      const float bs = bias[e];
#pragma unroll
      for (int mi = 0; mi < 4; ++mi) {
#pragma unroll
        for (int j = 0; j < 4; ++j) {
          const int m = brow + wr + mi * 16 + fq4 + j;
          const int b = m >> 11, s = m & 2047;
          float v = acc[mi][ni][j] + bs;
          const int d = e & 63;
          if (e < 2048) {
            const int h = e >> 6;
            qo[(((size_t)b * NH + h) * S_LEN + s) * HDIM + d] = f2bf(v * QSCALE);
          } else if (e < 2560) {
            const int gg = (e - 2048) >> 6;
            ko[(((size_t)b * NKV + gg) * S_LEN + s) * HDIM + d] = f2bf(v);
          } else {
            const int gg = (e - 2560) >> 6;
            // V transposed: Vt[b][g][d][s]
            vo[(((size_t)b * NKV + gg) * HDIM + d) * S_LEN + s] = f2bf(v);
          }
        }
      }
    }
  } else {
#pragma unroll
    for (int mi = 0; mi < 4; ++mi)
#pragma unroll
      for (int j = 0; j < 4; ++j) {
        const int m = brow + wr + mi * 16 + fq4 + j;
#pragma unroll
        for (int ni = 0; ni < 4; ++ni) {
          const int n = bcol + wc + ni * 16 + fr;
          co[(size_t)m * N + n] = acc[mi][ni][j] + bias[n];
        }
      }
  }
}

// ---------- sliding-window flash attention, v9 ----------
// v8 base (round-10 verified, 107 us) + pipe re-balance: K-fragments are now
// read DIRECTLY from global (L1-served: 4 waves re-read the same 8 KB tile),
// eliminating sK, its staging writes and 8 of 26 LDS ops per wave-tile.
// LDS keeps V (shared across waves) and the per-wave P round-trip.
// K loads issue before the staging barrier so L2 latency hides under it.
__global__ __launch_bounds__(256)
void attn_swin(const unsigned short* __restrict__ Qs, const unsigned short* __restrict__ Kb,
               const unsigned short* __restrict__ Vtb, unsigned short* __restrict__ ctx)
{
  __shared__ unsigned short sVt[64 * 64];         // 8 KB, [d][key] XOR-swizzled
  __shared__ unsigned short sP[4][16 * 64];       // 8 KB, per-wave [q][key] XOR-swizzled

  const int t = threadIdx.x, w = t >> 6, l = t & 63;
  const int fr = l & 15, fq = l >> 4;
  const int q0 = blockIdx.x << 6;
  const int h = blockIdx.y, b = blockIdx.z;
  const int g = h >> 2;

  const unsigned short* qp = Qs + (((size_t)(b * NH + h)) * S_LEN + q0 + (w << 4)) * HDIM;
  const bf16x8 qf0 = *(const bf16x8*)(qp + fr * HDIM + (fq << 3));
  const bf16x8 qf1 = *(const bf16x8*)(qp + fr * HDIM + 32 + (fq << 3));

  const unsigned short* Kg  = Kb  + ((size_t)(b * NKV + g)) * S_LEN * HDIM;  // [s][d]
  const unsigned short* Vtg = Vtb + ((size_t)(b * NKV + g)) * HDIM * S_LEN;  // [d][s]

  float m_run = -1e30f, l_part = 0.0f;   // per-lane; lane's q-row = fr
  f32x4 o_acc[4] = {};

  // V staging geometry: row0 = Vt d-row 0..31 (+32 second half), oct8 = 8-elem col
  const int row0 = t >> 3, oct8 = (t & 7) << 3;
  const int swz01 = (row0 & 7) << 4;
  const int off0 = ((row0 << 7) + (oct8 << 1)) ^ swz01;
  const int off1 = (((32 + row0) << 7) + (oct8 << 1)) ^ swz01;

  u16x8 vc0{}, vc1{}, vn0{}, vn1{};

  int lo = q0 - (WIN - 1); if (lo < 0) lo = 0; lo &= ~63;
  const int hi = q0 + 64;
  const int full_lo = q0 - (WIN - 64);
  const int full_hi = q0 - 64;

  // pointer-carried addresses
  const unsigned short* vP = Vtg + (size_t)row0 * S_LEN + lo + oct8;  // V staging
  const unsigned short* kD = Kg + (size_t)lo * HDIM + fr * HDIM + (fq << 3);  // K frags

  auto LOADV = [&](const unsigned short* vp, u16x8& b0, u16x8& b1)
      __attribute__((always_inline)) {
    b0 = *(const u16x8*)vp;
    b1 = *(const u16x8*)(vp + 32 * S_LEN);
  };

  auto TILE = [&](int kv0, const bf16x8* kf0, const bf16x8* kf1, bool MASKED)
      __attribute__((always_inline)) {
    f32x4 sf[4];
    // ---- QK^T (swapped): sf[nt][r] = S[q=fr][key = 16nt + 4fq + r] ----
    __builtin_amdgcn_s_setprio(1);
#pragma unroll
    for (int nt = 0; nt < 4; ++nt) {
      f32x4 z = {};
      z = __builtin_amdgcn_mfma_f32_16x16x32_bf16(kf0[nt], qf0, z, 0, 0, 0);
      z = __builtin_amdgcn_mfma_f32_16x16x32_bf16(kf1[nt], qf1, z, 0, 0, 0);
      sf[nt] = z;
    }
    __builtin_amdgcn_s_setprio(0);
    const int iq = q0 + (w << 4) + fr;     // this lane's q-row
    if (MASKED) {
#pragma unroll
      for (int nt = 0; nt < 4; ++nt) {
#pragma unroll
        for (int r = 0; r < 4; ++r) {
          const int jk = kv0 + (nt << 4) + (fq << 2) + r;
          if (jk > iq || jk <= iq - WIN) sf[nt][r] = -1e30f;
        }
      }
    }
    // ---- lane-local max over this lane's 16 keys ----
    float pmax;
    {
      f32x4 mx = sf[0];
      mx[0] = fmaxf(mx[0], sf[1][0]); mx[1] = fmaxf(mx[1], sf[1][1]);
      mx[2] = fmaxf(mx[2], sf[1][2]); mx[3] = fmaxf(mx[3], sf[1][3]);
      f32x4 my = sf[2];
      my[0] = fmaxf(my[0], sf[3][0]); my[1] = fmaxf(my[1], sf[3][1]);
      my[2] = fmaxf(my[2], sf[3][2]); my[3] = fmaxf(my[3], sf[3][3]);
      mx[0] = fmaxf(mx[0], my[0]); mx[1] = fmaxf(mx[1], my[1]);
      mx[2] = fmaxf(mx[2], my[2]); mx[3] = fmaxf(mx[3], my[3]);
      pmax = fmaxf(fmaxf(mx[0], mx[1]), fmaxf(mx[2], mx[3]));
    }
    // ---- T13 defer-max, lane-local gate (uniform via __any) ----
    if (__any(pmax - m_run > 8.0f)) {
      float rmax = fmaxf(pmax, __shfl_xor(pmax, 16));
      rmax = fmaxf(rmax, __shfl_xor(rmax, 32));
      const float mnew = fmaxf(m_run, rmax);
      const float rs = exp2f(m_run - mnew);
      m_run = mnew;
      l_part *= rs;
      float rs_o[4];
#pragma unroll
      for (int r = 0; r < 4; ++r) rs_o[r] = __shfl(rs, (fq << 2) + r, 16);
#pragma unroll
      for (int dt = 0; dt < 4; ++dt)
#pragma unroll
        for (int r = 0; r < 4; ++r) o_acc[dt][r] *= rs_o[r];
    }
    // ---- P = exp2(S - m); packed b64 stores; per-lane l partial ----
    float lloc = 0.0f;
    const int pswz = (fr & 7) << 4;
#pragma unroll
    for (int nt = 0; nt < 4; ++nt) {
      u16x4 pk;
#pragma unroll
      for (int r = 0; r < 4; ++r) {
        const float p = exp2f(sf[nt][r] - m_run);
        lloc += p;
        pk[r] = f2bf(p);
      }
      *(u16x4*)((char*)&sP[w][0] +
          (((fr << 7) + (nt << 5) + (fq << 3)) ^ pswz)) = pk;
    }
    l_part += lloc;
    // ---- PV: o += P @ V ----
#pragma unroll
    for (int ks = 0; ks < 2; ++ks) {
      bf16x8 pf = *(const bf16x8*)((const char*)&sP[w][0] +
          ((((fr << 7) + (ks << 6) + (fq << 4))) ^ pswz));
      bf16x8 vfr[4];
#pragma unroll
      for (int dt = 0; dt < 4; ++dt) {
        const int d = (dt << 4) + fr;
        vfr[dt] = *(const bf16x8*)((const char*)sVt +
            ((((d << 7) + (ks << 6) + (fq << 4))) ^ ((d & 7) << 4)));
      }
      __builtin_amdgcn_s_setprio(1);
#pragma unroll
      for (int dt = 0; dt < 4; ++dt)
        o_acc[dt] = __builtin_amdgcn_mfma_f32_16x16x32_bf16(pf, vfr[dt], o_acc[dt], 0, 0, 0);
      __builtin_amdgcn_s_setprio(0);
    }
  };

  LOADV(vP, vc0, vc1);

  for (int kv0 = lo; kv0 < hi; kv0 += 64) {
    // K fragments for THIS tile: direct global loads (L1-served), issued
    // before the barrier so latency hides under barrier + V staging.
    bf16x8 kf0[4], kf1[4];
#pragma unroll
    for (int nt = 0; nt < 4; ++nt) {
      kf0[nt] = *(const bf16x8*)(kD + (nt << 10));        // K[kv0+16nt+fr][8fq..]
      kf1[nt] = *(const bf16x8*)(kD + (nt << 10) + 32);   // d+32 half
    }
    kD += 64 * HDIM;
    vP += 64;
    __syncthreads();                      // prior tile's sVt reads done
    *(u16x8*)((char*)sVt + off0) = vc0;
    *(u16x8*)((char*)sVt + off1) = vc1;
    if (kv0 + 64 < hi) LOADV(vP, vn0, vn1);   // T14 prefetch next V
    __syncthreads();
    const bool masked = (kv0 < full_lo) || (kv0 > full_hi);
    if (masked) TILE(kv0, kf0, kf1, true); else TILE(kv0, kf0, kf1, false);
    vc0 = vn0; vc1 = vn1;
  }

  // ---- epilogue: reduce l over the 4 lanes sharing q, bcast inv, store ----
  float lsum = l_part;
  lsum += __shfl_xor(lsum, 16);
  lsum += __shfl_xor(lsum, 32);
  const float inv = 1.0f / lsum;
  float inv_o[4];
#pragma unroll
  for (int r = 0; r < 4; ++r) inv_o[r] = __shfl(inv, (fq << 2) + r, 16);

  unsigned short* cp = ctx + ((size_t)(b * S_LEN + q0 + (w << 4))) * D_MODEL + h * HDIM;
#pragma unroll
  for (int r = 0; r < 4; ++r) {
    const int row = (fq << 2) + r;
#pragma unroll
    for (int dt = 0; dt < 4; ++dt)
      cp[(size_t)row * D_MODEL + (dt << 4) + fr] = f2bf(o_acc[dt][r] * inv_o[r]);
  }
}

// ---------- launch ----------
extern "C" void kernel_launch(void* const* d_in, const int* in_sizes, int n_in,
                              void* d_out, int out_size, void* d_ws, size_t ws_size,
                              hipStream_t stream)
{
  const float* x    = (const float*)d_in[0];
  const float* Wqkv = (const float*)d_in[1];
  const float* bqkv = (const float*)d_in[2];
  const float* Wout = (const float*)d_in[3];
  const float* bout = (const float*)d_in[4];
  float* out = (float*)d_out;

  char* ws = (char*)d_ws;
  if (ws_size < 62914560u) return;

  unsigned short* xb    = (unsigned short*)(ws);
  unsigned short* ctx   = xb;                                  // alias after gemm1
  unsigned short* wqkvb = (unsigned short*)(ws + 16777216);
  unsigned short* woutb = (unsigned short*)(ws + 29360128);
  unsigned short* Qs    = (unsigned short*)(ws + 37748736);
  unsigned short* Kbuf  = (unsigned short*)(ws + 54525952);
  unsigned short* Vtbuf = (unsigned short*)(ws + 58720256);    // [b][g][d][s]

  cvt3<<<2048, 256, 0, stream>>>(x, xb, MTOT * D_MODEL,
                                 Wqkv, wqkvb, QKV_N * D_MODEL,
                                 Wout, woutb, D_MODEL * D_MODEL);

  gemm_nt<0><<<dim3(QKV_N / 128, MTOT / 128), 256, 0, stream>>>(
      xb, wqkvb, bqkv, D_MODEL, QKV_N, Qs, Kbuf, Vtbuf, nullptr);

  attn_swin<<<dim3(S_LEN / 64, NH, 2), 256, 0, stream>>>(Qs, Kbuf, Vtbuf, ctx);

  gemm_nt<1><<<dim3(D_MODEL / 128, MTOT / 128), 256, 0, stream>>>(
      ctx, woutb, bout, D_MODEL, D_MODEL, nullptr, nullptr, nullptr, out);
}

// Round 13
// 224.724 us; speedup vs baseline: 1.2720x; 1.2720x over previous
//
#include <hip/hip_runtime.h>
#include <stdint.h>

// ---------- problem constants ----------
#define S_LEN   2048
#define D_MODEL 2048
#define NH      32
#define NKV     8
#define HDIM    64
#define WIN     1024
#define QKV_N   3072
#define MTOT    4096          // B*S
#define QSCALE  0.18033688011112042f   // 0.125 * log2(e)

typedef __bf16 bf16x8 __attribute__((ext_vector_type(8)));
typedef float  f32x4  __attribute__((ext_vector_type(4)));
typedef unsigned short u16x8 __attribute__((ext_vector_type(8)));
typedef unsigned short u16x4 __attribute__((ext_vector_type(4)));

#define GLDS16(g, l) __builtin_amdgcn_global_load_lds( \
    (__attribute__((address_space(1))) void*)(g),      \
    (__attribute__((address_space(3))) void*)(l), 16, 0, 0)

// RNE f32->bf16 via the compiler cast (v_cvt_pk fusion).
__device__ __forceinline__ unsigned short f2bf(float f) {
  __bf16 b = (__bf16)f;
  return __builtin_bit_cast(unsigned short, b);
}

// ---------- fp32 -> bf16 conversion (3 segments, vectorized) ----------
__global__ void cvt3(const float* __restrict__ s0, unsigned short* __restrict__ d0, int n0,
                     const float* __restrict__ s1, unsigned short* __restrict__ d1, int n1,
                     const float* __restrict__ s2, unsigned short* __restrict__ d2, int n2)
{
  int total4 = (n0 + n1 + n2) >> 2;
  for (int idx = blockIdx.x * blockDim.x + threadIdx.x; idx < total4;
       idx += gridDim.x * blockDim.x) {
    int i = idx << 2;
    const float* s; unsigned short* d;
    if (i < n0)            { s = s0 + i;            d = d0 + i; }
    else if (i < n0 + n1)  { s = s1 + (i - n0);     d = d1 + (i - n0); }
    else                   { s = s2 + (i - n0 - n1); d = d2 + (i - n0 - n1); }
    float4 v = *(const float4*)s;
    u16x4 o;
    o[0] = f2bf(v.x); o[1] = f2bf(v.y); o[2] = f2bf(v.z); o[3] = f2bf(v.w);
    *(u16x4*)d = o;
  }
}

// ---------- NT GEMM: C[m,n] = sum_k A[m,k]*B[n,k] (+bias) ----------
// EP==0: QKV epilogue (scatter Q scaled / K row-major / V TRANSPOSED [d][s]).
// EP==1: fp32 out.
template<int EP>
__global__ __launch_bounds__(256)
void gemm_nt(const unsigned short* __restrict__ A, const unsigned short* __restrict__ Bm,
             const float* __restrict__ bias, int K, int N,
             unsigned short* __restrict__ qo, unsigned short* __restrict__ ko,
             unsigned short* __restrict__ vo, float* __restrict__ co)
{
  __shared__ unsigned short sA[128 * 32];
  __shared__ unsigned short sB[128 * 32];
  const int t = threadIdx.x;
  const int l = t & 63;
  const int brow = blockIdx.y << 7;
  const int bcol = blockIdx.x << 7;
  const int wr = ((t >> 7) & 1) << 6;
  const int wc = ((t >> 6) & 1) << 6;

  const int srow  = t >> 2;
  const int skoff = (t & 3) << 3;
  const unsigned short* aP = A + (size_t)(brow + srow) * K + skoff;
  const unsigned short* bP = Bm + (size_t)(bcol + srow) * K + skoff;
  unsigned short* ldsA0 = &sA[(t & 192) << 3];
  unsigned short* ldsA1 = &sA[(256 + (t & 192)) << 3];
  unsigned short* ldsB0 = &sB[(t & 192) << 3];
  unsigned short* ldsB1 = &sB[(256 + (t & 192)) << 3];

  f32x4 acc[4][4] = {};
  const int fr = l & 15;
  const int fk = (l >> 4) << 3;

  for (int kt = 0; kt < K; kt += 32) {
    GLDS16(aP, ldsA0);
    GLDS16(aP + (size_t)64 * K, ldsA1);
    GLDS16(bP, ldsB0);
    GLDS16(bP + (size_t)64 * K, ldsB1);
    aP += 32; bP += 32;
    __syncthreads();

    bf16x8 af[4], bf[4];
#pragma unroll
    for (int mi = 0; mi < 4; ++mi)
      af[mi] = *(const bf16x8*)&sA[(wr + mi * 16 + fr) * 32 + fk];
#pragma unroll
    for (int ni = 0; ni < 4; ++ni)
      bf[ni] = *(const bf16x8*)&sB[(wc + ni * 16 + fr) * 32 + fk];
#pragma unroll
    for (int mi = 0; mi < 4; ++mi)
#pragma unroll
      for (int ni = 0; ni < 4; ++ni)
        acc[mi][ni] = __builtin_amdgcn_mfma_f32_16x16x32_bf16(af[mi], bf[ni], acc[mi][ni], 0, 0, 0);
    __syncthreads();
  }

  const int fq4 = (l >> 4) << 2;
  if (EP == 0) {
#pragma unroll
    for (int ni = 0; ni < 4; ++ni) {
      const int e = bcol + wc + ni * 16 + fr;
      const float bs = bias[e];
#pragma unroll
      for (int mi = 0; mi < 4; ++mi) {
#pragma unroll
        for (int j = 0; j < 4; ++j) {
          const int m = brow + wr + mi * 16 + fq4 + j;
          const int b = m >> 11, s = m & 2047;
          float v = acc[mi][ni][j] + bs;
          const int d = e & 63;
          if (e < 2048) {
            const int h = e >> 6;
            qo[(((size_t)b * NH + h) * S_LEN + s) * HDIM + d] = f2bf(v * QSCALE);
          } else if (e < 2560) {
            const int gg = (e - 2048) >> 6;
            ko[(((size_t)b * NKV + gg) * S_LEN + s) * HDIM + d] = f2bf(v);
          } else {
            const int gg = (e - 2560) >> 6;
            // V transposed: Vt[b][g][d][s]
            vo[(((size_t)b * NKV + gg) * HDIM + d) * S_LEN + s] = f2bf(v);
          }
        }
      }
    }
  } else {
#pragma unroll
    for (int mi = 0; mi < 4; ++mi)
#pragma unroll
      for (int j = 0; j < 4; ++j) {
        const int m = brow + wr + mi * 16 + fq4 + j;
#pragma unroll
        for (int ni = 0; ni < 4; ++ni) {
          const int n = bcol + wc + ni * 16 + fr;
          co[(size_t)m * N + n] = acc[mi][ni][j] + bias[n];
        }
      }
  }
}

// ---------- sliding-window flash attention, v10b ----------
// v10 structure with the round-12 bug fixed: the K-fragment slot index was
// missing the kh (key-half) offset — kh=1 waves read keys 0..31 while
// masking as keys 32..63. slot = (kh<<5) + (ntg<<4) + fr.
//
// 512 thr = 8 waves: wave w -> (qh = w&3: q-rows 16qh.., kh = w>>2: keys
// 32kh..32kh+31 per tile). Independent online softmax per key-half; one
// LDS merge at epilogue (alpha=exp2(m-mf) zeroes never-healed halves).
// Key-slot permutation p(s)=32(s>>5)+8((s>>2)&3)+4((s>>4)&1)+(s&3) makes
// the swapped-QK output land P IN REGISTER as the PV A-fragment.
// Staging: global_load_lds double-buffer, pre-swizzled per-lane global
// sources + linear LDS dest + XOR-swizzled reads. One barrier per tile.
__global__ __launch_bounds__(512)
void attn_swin(const unsigned short* __restrict__ Qs, const unsigned short* __restrict__ Kb,
               const unsigned short* __restrict__ Vtb, unsigned short* __restrict__ ctx)
{
  __shared__ char lds[32768];   // 2 buffers x (K 8KB + V 8KB)

  const int t = threadIdx.x, w = t >> 6, l = t & 63;
  const int fr = l & 15, fq = l >> 4;
  const int qh = w & 3, kh = w >> 2;
  const int q0 = blockIdx.x << 6;
  const int h = blockIdx.y, b = blockIdx.z;
  const int g = h >> 2;

  // Q fragments: this wave's 16 q-rows = q0 + 16qh + fr
  const unsigned short* qp = Qs + (((size_t)(b * NH + h)) * S_LEN + q0 + (qh << 4)) * HDIM;
  const bf16x8 qf0 = *(const bf16x8*)(qp + fr * HDIM + (fq << 3));
  const bf16x8 qf1 = *(const bf16x8*)(qp + fr * HDIM + 32 + (fq << 3));

  const unsigned short* Kg  = Kb  + ((size_t)(b * NKV + g)) * S_LEN * HDIM;  // [s][d]
  const unsigned short* Vtg = Vtb + ((size_t)(b * NKV + g)) * HDIM * S_LEN;  // [d][s]

  float m_run = -1e30f, l_part = 0.0f;   // per-lane; q-row = fr (this wave's half)
  f32x4 o_acc[4] = {};

  int lo = q0 - (WIN - 1); if (lo < 0) lo = 0; lo &= ~63;
  const int hi = q0 + 64;
  const int full_lo = q0 - (WIN - 64);
  const int full_hi = q0 - 64;

  // ---- staging sources: 2 global_load_lds calls per wave (2KB slice) ----
  // waves 0-3 stage K (permuted+pre-swizzled), waves 4-7 stage V (pre-swizzled)
  const unsigned short* src0;
  const unsigned short* src1;
  {
    const int x0 = ((w & 3) << 11) + (l << 4);   // byte offset in 8KB region, c=0
    const int x1 = x0 + 1024;                    // c=1
    if (w < 4) {
      const int s0 = x0 >> 7, o0 = ((x0 >> 4) & 7) ^ (s0 & 7);
      const int s1 = x1 >> 7, o1 = ((x1 >> 4) & 7) ^ (s1 & 7);
      const int p0 = ((s0 >> 5) << 5) | (((s0 >> 2) & 3) << 3) | (((s0 >> 4) & 1) << 2) | (s0 & 3);
      const int p1 = ((s1 >> 5) << 5) | (((s1 >> 2) & 3) << 3) | (((s1 >> 4) & 1) << 2) | (s1 & 3);
      src0 = Kg + (size_t)(lo + p0) * HDIM + (o0 << 3);
      src1 = Kg + (size_t)(lo + p1) * HDIM + (o1 << 3);
    } else {
      const int d0 = x0 >> 7, o0 = ((x0 >> 4) & 7) ^ (d0 & 7);
      const int d1 = x1 >> 7, o1 = ((x1 >> 4) & 7) ^ (d1 & 7);
      src0 = Vtg + (size_t)d0 * S_LEN + lo + (o0 << 3);
      src1 = Vtg + (size_t)d1 * S_LEN + lo + (o1 << 3);
    }
  }
  const int sadv = (w < 4) ? 64 * HDIM : 64;            // per-tile src advance
  const int dbase = ((w < 4) ? 0 : 8192) + ((w & 3) << 11) + (l << 4);

  char* bufA = lds;            // current tile
  char* bufB = lds + 16384;    // prefetch target

  // prologue: stage tile 0 into bufA
  GLDS16(src0, bufA + dbase);
  GLDS16(src1, bufA + dbase + 1024);
  src0 += sadv; src1 += sadv;

  const int iq = q0 + (qh << 4) + fr;        // this lane's q-row
  const int swr = (fr & 7) << 4;             // read-side XOR swizzle

  auto TILE = [&](int kv0, const char* sK, const char* sV, bool MASKED)
      __attribute__((always_inline)) {
    // ---- K fragments: this wave's key-half slots (FIX: + (kh<<5)) ----
    bf16x8 kf[2][2];
#pragma unroll
    for (int ntg = 0; ntg < 2; ++ntg) {
      const int slot = (kh << 5) + (ntg << 4) + fr;
      kf[ntg][0] = *(const bf16x8*)(sK + (((slot << 7) + (fq << 4)) ^ swr));
      kf[ntg][1] = *(const bf16x8*)(sK + (((slot << 7) + ((fq + 4) << 4)) ^ swr));
    }
    // ---- QK^T (swapped): sf[ntg][r] = S[q=iq][pkey = kv0+32kh+8fq+4ntg+r] ----
    __builtin_amdgcn_s_setprio(1);
    f32x4 sf[2];
#pragma unroll
    for (int ntg = 0; ntg < 2; ++ntg) {
      f32x4 z = {};
      z = __builtin_amdgcn_mfma_f32_16x16x32_bf16(kf[ntg][0], qf0, z, 0, 0, 0);
      z = __builtin_amdgcn_mfma_f32_16x16x32_bf16(kf[ntg][1], qf1, z, 0, 0, 0);
      sf[ntg] = z;
    }
    __builtin_amdgcn_s_setprio(0);
    if (MASKED) {
#pragma unroll
      for (int ntg = 0; ntg < 2; ++ntg)
#pragma unroll
        for (int r = 0; r < 4; ++r) {
          const int jk = kv0 + (kh << 5) + (fq << 3) + (ntg << 2) + r;
          if (jk > iq || jk <= iq - WIN) sf[ntg][r] = -1e30f;
        }
    }
    // ---- lane-local max over this lane's 8 keys ----
    float pmax;
    {
      f32x4 mx = sf[0];
      mx[0] = fmaxf(mx[0], sf[1][0]); mx[1] = fmaxf(mx[1], sf[1][1]);
      mx[2] = fmaxf(mx[2], sf[1][2]); mx[3] = fmaxf(mx[3], sf[1][3]);
      pmax = fmaxf(fmaxf(mx[0], mx[1]), fmaxf(mx[2], mx[3]));
    }
    // ---- T13 defer-max, lane-local gate ----
    if (__any(pmax - m_run > 8.0f)) {
      float rmax = fmaxf(pmax, __shfl_xor(pmax, 16));
      rmax = fmaxf(rmax, __shfl_xor(rmax, 32));
      const float mnew = fmaxf(m_run, rmax);
      const float rs = exp2f(m_run - mnew);
      m_run = mnew;
      l_part *= rs;
      float rs_o[4];
#pragma unroll
      for (int r = 0; r < 4; ++r) rs_o[r] = __shfl(rs, (fq << 2) + r, 16);
#pragma unroll
      for (int dt = 0; dt < 4; ++dt)
#pragma unroll
        for (int r = 0; r < 4; ++r) o_acc[dt][r] *= rs_o[r];
    }
    // ---- P = exp2(S - m), packed IN REGISTER as the PV A-fragment ----
    union { unsigned short us[8]; bf16x8 v; } pu;
    float lloc = 0.0f;
#pragma unroll
    for (int ntg = 0; ntg < 2; ++ntg)
#pragma unroll
      for (int r = 0; r < 4; ++r) {
        const float p = exp2f(sf[ntg][r] - m_run);
        lloc += p;
        pu.us[(ntg << 2) + r] = f2bf(p);   // k-index = 4ntg + r (phys order)
      }
    l_part += lloc;
    // ---- V fragments + PV (K=32 over this wave's key-half) ----
    bf16x8 vf[4];
#pragma unroll
    for (int dt = 0; dt < 4; ++dt) {
      const int d = (dt << 4) + fr;
      vf[dt] = *(const bf16x8*)(sV + ((d << 7) + ((((kh << 2) + fq) ^ (fr & 7)) << 4)));
    }
    __builtin_amdgcn_s_setprio(1);
#pragma unroll
    for (int dt = 0; dt < 4; ++dt)
      o_acc[dt] = __builtin_amdgcn_mfma_f32_16x16x32_bf16(pu.v, vf[dt], o_acc[dt], 0, 0, 0);
    __builtin_amdgcn_s_setprio(0);
  };

  for (int kv0 = lo; kv0 < hi; kv0 += 64) {
    __syncthreads();   // implicit vmcnt(0): bufA staged; bufB free (prev reads done)
    if (kv0 + 64 < hi) {
      GLDS16(src0, bufB + dbase);
      GLDS16(src1, bufB + dbase + 1024);
      src0 += sadv; src1 += sadv;
    }
    const bool masked = (kv0 < full_lo) || (kv0 > full_hi);
    if (masked) TILE(kv0, bufA, bufA + 8192, true);
    else        TILE(kv0, bufA, bufA + 8192, false);
    char* tmp = bufA; bufA = bufB; bufB = tmp;
  }

  // ---- epilogue: merge the two key-halves per q-group via LDS ----
  float lsum = l_part;
  lsum += __shfl_xor(lsum, 16);
  lsum += __shfl_xor(lsum, 32);

  __syncthreads();   // all tile reads done; lds reusable as merge scratch
  if (w < 4) {       // kh=0 waves publish (o, m, l)
    char* ob = lds + ((w & 3) << 12);
#pragma unroll
    for (int dt = 0; dt < 4; ++dt)
      *(f32x4*)(ob + (dt << 10) + (l << 4)) = o_acc[dt];
    if (fq == 0) {
      *(float*)(lds + 16384 + ((w & 3) << 7) + (fr << 3))     = m_run;
      *(float*)(lds + 16384 + ((w & 3) << 7) + (fr << 3) + 4) = lsum;
    }
  }
  __syncthreads();
  if (w >= 4) {      // kh=1 waves merge + write ctx
    const char* ob = lds + ((w & 3) << 12);
    const float m_p = *(const float*)(lds + 16384 + ((w & 3) << 7) + (fr << 3));
    const float l_p = *(const float*)(lds + 16384 + ((w & 3) << 7) + (fr << 3) + 4);
    const float m_f = fmaxf(m_run, m_p);
    const float a  = exp2f(m_run - m_f);
    const float bb = exp2f(m_p  - m_f);
    const float inv = 1.0f / (a * lsum + bb * l_p);
    const float alpha = a * inv, beta = bb * inv;
    float al[4], be[4];
#pragma unroll
    for (int r = 0; r < 4; ++r) {
      al[r] = __shfl(alpha, (fq << 2) + r, 16);
      be[r] = __shfl(beta,  (fq << 2) + r, 16);
    }
    unsigned short* cp = ctx + ((size_t)(b * S_LEN + q0 + (qh << 4))) * D_MODEL + h * HDIM;
#pragma unroll
    for (int dt = 0; dt < 4; ++dt) {
      const f32x4 op = *(const f32x4*)(ob + (dt << 10) + (l << 4));
#pragma unroll
      for (int r = 0; r < 4; ++r) {
        const float of = al[r] * o_acc[dt][r] + be[r] * op[r];
        cp[(size_t)((fq << 2) + r) * D_MODEL + (dt << 4) + fr] = f2bf(of);
      }
    }
  }
}

// ---------- launch ----------
extern "C" void kernel_launch(void* const* d_in, const int* in_sizes, int n_in,
                              void* d_out, int out_size, void* d_ws, size_t ws_size,
                              hipStream_t stream)
{
  const float* x    = (const float*)d_in[0];
  const float* Wqkv = (const float*)d_in[1];
  const float* bqkv = (const float*)d_in[2];
  const float* Wout = (const float*)d_in[3];
  const float* bout = (const float*)d_in[4];
  float* out = (float*)d_out;

  char* ws = (char*)d_ws;
  if (ws_size < 62914560u) return;

  unsigned short* xb    = (unsigned short*)(ws);
  unsigned short* ctx   = xb;                                  // alias after gemm1
  unsigned short* wqkvb = (unsigned short*)(ws + 16777216);
  unsigned short* woutb = (unsigned short*)(ws + 29360128);
  unsigned short* Qs    = (unsigned short*)(ws + 37748736);
  unsigned short* Kbuf  = (unsigned short*)(ws + 54525952);
  unsigned short* Vtbuf = (unsigned short*)(ws + 58720256);    // [b][g][d][s]

  cvt3<<<2048, 256, 0, stream>>>(x, xb, MTOT * D_MODEL,
                                 Wqkv, wqkvb, QKV_N * D_MODEL,
                                 Wout, woutb, D_MODEL * D_MODEL);

  gemm_nt<0><<<dim3(QKV_N / 128, MTOT / 128), 256, 0, stream>>>(
      xb, wqkvb, bqkv, D_MODEL, QKV_N, Qs, Kbuf, Vtbuf, nullptr);

  attn_swin<<<dim3(S_LEN / 64, NH, 2), 512, 0, stream>>>(Qs, Kbuf, Vtbuf, ctx);

  gemm_nt<1><<<dim3(D_MODEL / 128, MTOT / 128), 256, 0, stream>>>(
      ctx, woutb, bout, D_MODEL, D_MODEL, nullptr, nullptr, nullptr, out);
}